// Round 17
// baseline (206.871 us; speedup 1.0000x reference)
//
#include <hip/hip_runtime.h>
#include <stdint.h>

// ---------------------------------------------------------------------------
// SNN EMNIST forward: T=10, B=4096, IN=784, HID=256, NCLS=47
// R17 = R16 with the threefry hash as FOUR interleaved chains per asm block:
// R5/R13/R16 showed the spikegen wall (72-76us) is invariant to static op
// count (116 -> 72 ops/hash) => not issue-bound => serial-dep-chain latency
// bound (each asm block was one 72-op serial chain; compiler can't
// interleave across asm blocks). 4-way interleave spaces every dependent
// pair 4 instrs (>=8 cyc) apart -> in-wave ILP covers VALU latency.
// Same instruction count, same bits -> absmax exactly 4.882812e-4.
//   1) spike_split_k: R5 grid (2000 blocks) + x4-interleaved hash; blocks
//      2000..2255 do the exact 3-way bf16 W1 split.
//   2) gemm_mfma_k: R5's word-expand MFMA gemm verbatim (N=128, 5 blk/CU).
//   3) scanout_k: fused LIF scan + readout (R8-validated).
// ---------------------------------------------------------------------------

#define T_STEPS 10
#define BATCH   4096
#define IN_DIM  784
#define HID     256
#define NCLS    47
#define NROWS   (T_STEPS * BATCH)        // 40960
#define KWORDS  25                       // ceil(784/32)
#define KPAD    800                      // 25*32

// d_ws layout (bytes):
//   [0, 41943040)          I_all : float [40960][256]
//   [41943040, 46039040)   spk   : u32 [25][10][4096]
//   [46039040, ...)        W1{hi,mid,lo}T : bf16 [256][800], 409600 B each
#define WS_IALL_OFF 0u
#define WS_SPK_OFF  41943040u
#define WS_W1HI_OFF 46039040u
#define WS_W1MD_OFF (46039040u + 409600u)
#define WS_W1LO_OFF (46039040u + 819200u)

typedef __attribute__((ext_vector_type(8))) short    bf16x8;
typedef __attribute__((ext_vector_type(4))) float    f32x4;
typedef __attribute__((ext_vector_type(4))) uint32_t u32x4;

// ---------------------------------------------------------------------------
// Threefry2x32 x4 interleaved, key=(0,42), partitionable: counter=(0,lo),
// out=(o0^o1)>>9. Chains a,b,c,d on (%0,%1),(%2,%3),(%4,%5),(%6,%7); input
// %8 = ib. Every dependent pair is 4 instructions apart. 288 instrs total.
// Injection constants validated bitwise in R13/R14/R16.
// ---------------------------------------------------------------------------
#define Q_ADD \
    "v_add_u32 %0, %0, %1\n\t" \
    "v_add_u32 %2, %2, %3\n\t" \
    "v_add_u32 %4, %4, %5\n\t" \
    "v_add_u32 %6, %6, %7\n\t"

#define Q_ALN(sh) \
    "v_alignbit_b32 %1, %1, %1, " sh "\n\t" \
    "v_alignbit_b32 %3, %3, %3, " sh "\n\t" \
    "v_alignbit_b32 %5, %5, %5, " sh "\n\t" \
    "v_alignbit_b32 %7, %7, %7, " sh "\n\t"

#define Q_XOR \
    "v_xor_b32 %1, %1, %0\n\t" \
    "v_xor_b32 %3, %3, %2\n\t" \
    "v_xor_b32 %5, %5, %4\n\t" \
    "v_xor_b32 %7, %7, %6\n\t"

#define Q_RND(sh) Q_ADD Q_ALN(sh) Q_XOR

#define Q_INJ0(c) \
    "v_add_u32 %0, " c ", %0\n\t" \
    "v_add_u32 %2, " c ", %2\n\t" \
    "v_add_u32 %4, " c ", %4\n\t" \
    "v_add_u32 %6, " c ", %6\n\t"

#define Q_INJ1(c) \
    "v_add_u32 %1, " c ", %1\n\t" \
    "v_add_u32 %3, " c ", %3\n\t" \
    "v_add_u32 %5, " c ", %5\n\t" \
    "v_add_u32 %7, " c ", %7\n\t"

// Four hashes: m0..m3 = (threefry(0, ib+Ja..Jd) folded) >> 9.
#define TF_HASH9X4(m0v, m1v, m2v, m3v, ibv, Ja, Jb, Jc, Jd) do {     \
    uint32_t _a0, _a1, _b0, _b1, _c0, _c1, _d0, _d1;                 \
    asm("v_add_u32 %1, " Ja ", %8\n\t"        /* x1 = ib + 42+j */   \
        "v_add_u32 %3, " Jb ", %8\n\t"                               \
        "v_add_u32 %5, " Jc ", %8\n\t"                               \
        "v_add_u32 %7, " Jd ", %8\n\t"                               \
        "v_mov_b32 %0, %1\n\t"                /* R1 add (x0=0+x1) */ \
        "v_mov_b32 %2, %3\n\t"                                       \
        "v_mov_b32 %4, %5\n\t"                                       \
        "v_mov_b32 %6, %7\n\t"                                       \
        Q_ALN("19") Q_XOR                     /* R1 tail */          \
        Q_RND("17") Q_RND("6") Q_RND("26")    /* R2-R4 */            \
        Q_INJ0("42") Q_INJ1("0x1bd11bf1")                            \
        Q_RND("15") Q_RND("3") Q_RND("16") Q_RND("8")    /* R5-R8 */ \
        Q_INJ0("0x1bd11bf0") Q_INJ1("2")                             \
        Q_RND("19") Q_RND("17") Q_RND("6") Q_RND("26")   /* R9-12 */ \
        Q_INJ1("45")                                                 \
        Q_RND("15") Q_RND("3") Q_RND("16") Q_RND("8")    /* R13-16 */\
        Q_INJ0("42") Q_INJ1("0x1bd11bf4")                            \
        Q_RND("19") Q_RND("17") Q_RND("6") Q_RND("26")   /* R17-20 */\
        Q_INJ0("0x1bd11bf0") Q_INJ1("5")                             \
        "v_xor_b32 %0, %0, %1\n\t"            /* fold */             \
        "v_xor_b32 %2, %2, %3\n\t"                                   \
        "v_xor_b32 %4, %4, %5\n\t"                                   \
        "v_xor_b32 %6, %6, %7\n\t"                                   \
        "v_lshrrev_b32 %0, 9, %0\n\t"                                \
        "v_lshrrev_b32 %2, 9, %2\n\t"                                \
        "v_lshrrev_b32 %4, 9, %4\n\t"                                \
        "v_lshrrev_b32 %6, 9, %6"                                    \
        : "=&v"(_a0), "=&v"(_a1), "=&v"(_b0), "=&v"(_b1),            \
          "=&v"(_c0), "=&v"(_c1), "=&v"(_d0), "=&v"(_d1)             \
        : "v"(ibv));                                                 \
    m0v = _a0; m1v = _b0; m2v = _c0; m3v = _d0;                      \
} while (0)

// 8 hashes (j=0..7) at base ib vs xa/xb, OR-ing bits into wrd at
// bit positions base_bit..base_bit+7 (compile-time constant).
#define SPIKE8(wrd, ib, xa, xb, base_bit) do {                             \
    uint32_t m0h, m1h, m2h, m3h, m4h, m5h, m6h, m7h;                       \
    TF_HASH9X4(m0h, m1h, m2h, m3h, (ib), "42", "43", "44", "45");          \
    TF_HASH9X4(m4h, m5h, m6h, m7h, (ib), "46", "47", "48", "49");          \
    if ((float)m0h < (xa).x * 8388608.0f) wrd |= (1u << ((base_bit) + 0)); \
    if ((float)m1h < (xa).y * 8388608.0f) wrd |= (1u << ((base_bit) + 1)); \
    if ((float)m2h < (xa).z * 8388608.0f) wrd |= (1u << ((base_bit) + 2)); \
    if ((float)m3h < (xa).w * 8388608.0f) wrd |= (1u << ((base_bit) + 3)); \
    if ((float)m4h < (xb).x * 8388608.0f) wrd |= (1u << ((base_bit) + 4)); \
    if ((float)m5h < (xb).y * 8388608.0f) wrd |= (1u << ((base_bit) + 5)); \
    if ((float)m6h < (xb).z * 8388608.0f) wrd |= (1u << ((base_bit) + 6)); \
    if ((float)m7h < (xb).w * 8388608.0f) wrd |= (1u << ((base_bit) + 7)); \
} while (0)

// ---------------------------------------------------------------------------
// Kernel 1: spikegen (blocks 0..1999, R5 grid) + W1 split (blocks 2000..2255).
// ---------------------------------------------------------------------------
__global__ __launch_bounds__(256) void spike_split_k(
        const float* __restrict__ x, uint32_t* __restrict__ spk,
        const float* __restrict__ W1, ushort* __restrict__ hiT,
        ushort* __restrict__ midT, ushort* __restrict__ loT) {
    const int tid = threadIdx.x;

    if (blockIdx.x >= 2000) {            // ---- W1 split ----
        int n = blockIdx.x - 2000;       // 0..255
        for (int k = tid; k < KPAD; k += 256) {
            float w = (k < IN_DIM) ? W1[k * HID + n] : 0.0f;
            uint32_t u = __float_as_uint(w);
            uint32_t hb = (u + 0x7FFFu + ((u >> 16) & 1u)) >> 16;    // RNE
            float hf = __uint_as_float(hb << 16);
            float r1 = w - hf;                                       // exact
            uint32_t u1 = __float_as_uint(r1);
            uint32_t mb = (u1 + 0x7FFFu + ((u1 >> 16) & 1u)) >> 16;  // RNE
            float mf2 = __uint_as_float(mb << 16);
            float r2 = r1 - mf2;                                     // exact
            uint32_t u2 = __float_as_uint(r2);
            uint32_t lb = (u2 + 0x7FFFu + ((u2 >> 16) & 1u)) >> 16;  // exact
            hiT [n * KPAD + k] = (ushort)hb;
            midT[n * KPAD + k] = (ushort)mb;
            loT [n * KPAD + k] = (ushort)lb;
        }
        return;
    }

    // ---- spikegen ----
    const int bid = blockIdx.x;          // (kw*5 + tg)*16 + bblk
    const int kw  = bid / 80;
    const int rem = bid - kw * 80;
    const int tg  = rem >> 4;
    const int b   = ((rem & 15) << 8) + tid;
    const int t0  = tg << 1;
    const int kbase = kw << 5;

    const uint32_t tstep = (uint32_t)(BATCH * IN_DIM);
    const uint32_t i0 = (uint32_t)(b * IN_DIM + kbase) + (uint32_t)t0 * tstep;
    const float* xr = x + b * IN_DIM + kbase;

    uint32_t w0 = 0u, w1 = 0u;
    const int ng = (kw == 24) ? 2 : 4;   // groups of 8 k's (wave-uniform)

    for (int g = 0; g < ng; ++g) {
        float4 xa = *(const float4*)&xr[g << 3];
        float4 xb = *(const float4*)&xr[(g << 3) + 4];
        uint32_t ib0 = i0 + (uint32_t)(g << 3);
        uint32_t ib1 = ib0 + tstep;
        switch (g) {                     // base_bit must be compile-time
            case 0: SPIKE8(w0, ib0, xa, xb, 0);  SPIKE8(w1, ib1, xa, xb, 0);  break;
            case 1: SPIKE8(w0, ib0, xa, xb, 8);  SPIKE8(w1, ib1, xa, xb, 8);  break;
            case 2: SPIKE8(w0, ib0, xa, xb, 16); SPIKE8(w1, ib1, xa, xb, 16); break;
            default:SPIKE8(w0, ib0, xa, xb, 24); SPIKE8(w1, ib1, xa, xb, 24); break;
        }
    }
    spk[(kw * T_STEPS + t0    ) * BATCH + b] = w0;
    spk[(kw * T_STEPS + t0 + 1) * BATCH + b] = w1;
}

// ---------------------------------------------------------------------------
// Kernel 2: gemm from packed words (R5's validated kernel, verbatim).
// Block: 64 rows (one t) x 128 cols, 4 waves; wave = 64x32 = 4x2 tiles of
// 16x16x32. Grid 1280 = exactly 5 blocks/CU, LDS 28KB.
// ---------------------------------------------------------------------------
#define LDS_A  0
#define LDS_BH 4096
#define LDS_BM 12288
#define LDS_BL 20480

__global__ __launch_bounds__(256, 5) void gemm_mfma_k(
        const ushort* __restrict__ hiT, const ushort* __restrict__ midT,
        const ushort* __restrict__ loT, const float* __restrict__ b1,
        const uint32_t* __restrict__ spk, float* __restrict__ I_all) {
    __shared__ __align__(16) char lds[28672];

    const int tid = threadIdx.x;
    const int l   = tid & 63;
    const int wv  = tid >> 6;
    const int bid = blockIdx.x;
    const int t    = bid >> 7;           // 128 blocks per t
    const int rem  = bid & 127;
    const int b0   = (rem >> 1) << 6;
    const int nc0  = (rem & 1) << 7;     // col offset 0 or 128
    const int m0   = (t << 12) + b0;

    f32x4 acc[4][2] = {};

    const int q   = l >> 4;
    const int sig = q ^ (l & 3) ^ ((l >> 2) & 3);
    const int a_base = LDS_A + ((l & 15) << 6) + (sig << 4);
    const int b_base = (((wv << 5) + (l & 15)) << 6) + (sig << 4);

    const int er = tid >> 2;
    const int eq = tid & 3;
    const int ea = LDS_A + (er << 6) + ((eq ^ (er & 3) ^ ((er >> 2) & 3)) << 4);
    const uint32_t* wptr = spk + (size_t)t * BATCH + b0 + er;

    for (int kw = 0; kw < KWORDS; ++kw) {
        __syncthreads();

        // --- stage Bhi/Bmid/Blo chunk (k in [kw*32,kw*32+32), 128 n) ---
#pragma unroll
        for (int i = 0; i < 2; ++i) {
            int s  = (i << 8) + tid;                    // slot 0..511
            int n  = s >> 2;
            int qs = s & 3;
            int qd = qs ^ (n & 3) ^ ((n >> 2) & 3);
            size_t gb = (size_t)(nc0 + n) * (KPAD * 2) + ((size_t)kw << 6) + ((size_t)qd << 4);
            int ldst = s << 4;
            __builtin_amdgcn_global_load_lds(
                (const __attribute__((address_space(1))) void*)((const char*)hiT + gb),
                (__attribute__((address_space(3))) void*)(lds + LDS_BH + ldst),
                16, 0, 0);
            __builtin_amdgcn_global_load_lds(
                (const __attribute__((address_space(1))) void*)((const char*)midT + gb),
                (__attribute__((address_space(3))) void*)(lds + LDS_BM + ldst),
                16, 0, 0);
            __builtin_amdgcn_global_load_lds(
                (const __attribute__((address_space(1))) void*)((const char*)loT + gb),
                (__attribute__((address_space(3))) void*)(lds + LDS_BL + ldst),
                16, 0, 0);
        }

        // --- expand spike bits -> bf16 A tile (64 rows x 32 k) ---
        {
            uint32_t w = wptr[(size_t)kw * NROWS];
            uint32_t byte = (w >> (eq << 3)) & 0xFFu;
            u32x4 v;
            v.x = ((byte &   1u) ? 0x3F80u : 0u) | ((byte &   2u) ? 0x3F800000u : 0u);
            v.y = ((byte &   4u) ? 0x3F80u : 0u) | ((byte &   8u) ? 0x3F800000u : 0u);
            v.z = ((byte &  16u) ? 0x3F80u : 0u) | ((byte &  32u) ? 0x3F800000u : 0u);
            v.w = ((byte &  64u) ? 0x3F80u : 0u) | ((byte & 128u) ? 0x3F800000u : 0u);
            *(u32x4*)(lds + ea) = v;
        }

        __syncthreads();

        // --- compute: 4 mtiles x 2 ntiles x (hi,mid,lo) = 24 MFMA ---
        bf16x8 af[4];
#pragma unroll
        for (int mt = 0; mt < 4; ++mt)
            af[mt] = *(const bf16x8*)(lds + a_base + (mt << 10));
#pragma unroll
        for (int nt = 0; nt < 2; ++nt) {
            bf16x8 bh = *(const bf16x8*)(lds + LDS_BH + b_base + (nt << 10));
            bf16x8 bm = *(const bf16x8*)(lds + LDS_BM + b_base + (nt << 10));
            bf16x8 bl = *(const bf16x8*)(lds + LDS_BL + b_base + (nt << 10));
#pragma unroll
            for (int mt = 0; mt < 4; ++mt) {
                acc[mt][nt] = __builtin_amdgcn_mfma_f32_16x16x32_bf16(af[mt], bh, acc[mt][nt], 0, 0, 0);
                acc[mt][nt] = __builtin_amdgcn_mfma_f32_16x16x32_bf16(af[mt], bm, acc[mt][nt], 0, 0, 0);
                acc[mt][nt] = __builtin_amdgcn_mfma_f32_16x16x32_bf16(af[mt], bl, acc[mt][nt], 0, 0, 0);
            }
        }
    }

    // --- epilogue: acc -> I_all (+ b1) ---
    const int c0 = l & 15;
    float b1v[2];
#pragma unroll
    for (int nt = 0; nt < 2; ++nt)
        b1v[nt] = b1[nc0 + (wv << 5) + (nt << 4) + c0];
#pragma unroll
    for (int mt = 0; mt < 4; ++mt) {
#pragma unroll
        for (int nt = 0; nt < 2; ++nt) {
            int col = nc0 + (wv << 5) + (nt << 4) + c0;
#pragma unroll
            for (int r = 0; r < 4; ++r) {
                int row = m0 + (mt << 4) + (q << 2) + r;
                I_all[(size_t)row * HID + col] = acc[mt][nt][r] + b1v[nt];
            }
        }
    }
}

// ---------------------------------------------------------------------------
// Kernel 3: fused LIF scan + readout (R8-validated), 16 batch rows/block.
// ---------------------------------------------------------------------------
__global__ __launch_bounds__(256) void scanout_k(
        const float* __restrict__ I_all, const float* __restrict__ Wr,
        const float* __restrict__ br, float* __restrict__ out) {
    __shared__ float gl[16 * 256];       // 16 KB
    const int tid = threadIdx.x;
    const int b0  = blockIdx.x << 4;

#pragma unroll 4
    for (int b = 0; b < 16; ++b) {
        const float* p = I_all + ((size_t)(b0 + b) << 8) + tid;
        float v = 0.f, ga = 0.f, wt = 0.0009765625f;   // 2^-10
#pragma unroll
        for (int t = 0; t < T_STEPS; ++t) {
            float I = p[(size_t)t * BATCH * HID];
            v = v + (I - v) * 0.5f;
            if (v >= 1.0f) { ga += wt; v = 0.f; }
            wt += wt;
        }
        gl[(b << 8) + tid] = ga;
    }
    __syncthreads();

    const int wv = tid >> 6;
    const int c  = tid & 63;
    if (c >= NCLS) return;
    float acc[4] = {0.f, 0.f, 0.f, 0.f};
    for (int h4 = 0; h4 < 64; ++h4) {
        float w0 = Wr[((h4 << 2) + 0) * NCLS + c];
        float w1 = Wr[((h4 << 2) + 1) * NCLS + c];
        float w2 = Wr[((h4 << 2) + 2) * NCLS + c];
        float w3 = Wr[((h4 << 2) + 3) * NCLS + c];
#pragma unroll
        for (int j = 0; j < 4; ++j) {
            float4 gg = *(float4*)&gl[(((wv << 2) + j) << 8) + (h4 << 2)];
            acc[j] = fmaf(gg.x, w0, acc[j]);
            acc[j] = fmaf(gg.y, w1, acc[j]);
            acc[j] = fmaf(gg.z, w2, acc[j]);
            acc[j] = fmaf(gg.w, w3, acc[j]);
        }
    }
    float brv = br[c] * 0.9990234375f;
#pragma unroll
    for (int j = 0; j < 4; ++j)
        out[(b0 + (wv << 2) + j) * NCLS + c] = acc[j] + brv;
}

extern "C" void kernel_launch(void* const* d_in, const int* in_sizes, int n_in,
                              void* d_out, int out_size, void* d_ws, size_t ws_size,
                              hipStream_t stream) {
    const float* x  = (const float*)d_in[0];
    const float* W1 = (const float*)d_in[1];
    const float* b1 = (const float*)d_in[2];
    const float* Wr = (const float*)d_in[3];
    const float* br = (const float*)d_in[4];
    float* out = (float*)d_out;

    float*    I_all = (float*)   ((char*)d_ws + WS_IALL_OFF);
    uint32_t* spk   = (uint32_t*)((char*)d_ws + WS_SPK_OFF);
    ushort*   w1hi  = (ushort*)  ((char*)d_ws + WS_W1HI_OFF);
    ushort*   w1md  = (ushort*)  ((char*)d_ws + WS_W1MD_OFF);
    ushort*   w1lo  = (ushort*)  ((char*)d_ws + WS_W1LO_OFF);

    spike_split_k<<<2256, 256, 0, stream>>>(x, spk, W1, w1hi, w1md, w1lo);
    gemm_mfma_k<<<1280, 256, 0, stream>>>(w1hi, w1md, w1lo, b1, spk, I_all);
    scanout_k<<<BATCH / 16, 256, 0, stream>>>(I_all, Wr, br, out);
}